// Round 4
// baseline (719.818 us; speedup 1.0000x reference)
//
#include <hip/hip_runtime.h>
#include <hip/hip_bf16.h>

// LocalAggregation: B=8, N=2048, K=32, D=64, C1=64, C2=128, R=0.15, EPS=1e-5
// ALL buffers are float32 storage (values bf16-ified by harness).
// K1 ball-query in f32 with FMA-chain dot (matches numpy/XLA einsum inner loop:
// d = fma(z,z, fma(y,y, rnd(x*x)))); S and sq use separate rounds like np.
// Pipeline: K1 ball-query -> K2 h1 stats -> K3 h1+bn1+relu -> h2 (+stats) -> max-pool
//           (pre-BN, stored f32 in d_out) -> K5 bn2+relu in place. K4 copies position.
// Trick: gamma2>0 => relu(bn2(.)) monotone => max-pool commutes with bn2+relu.

#define BB 8
#define NN 2048
#define KK 32
#define DD 64
#define CC1 64
#define CC2 128
#define IN1 67             // D + 3
#define TOTROWS (BB*NN*KK) // 524288
#define SITES (BB*NN)      // 16384

__device__ __forceinline__ float rl(float v, int l) {
  return __int_as_float(__builtin_amdgcn_readlane(__float_as_int(v), l));
}

// ---------------- K1: ball query (f32, FMA-chain dot) ----------------
// 256 blocks x 64 threads; block = (batch, 64-query tile). All N positions in LDS.
// Include m iff !(sq > r^2); first 32 ascending; pad with first neighbor.
__global__ __launch_bounds__(64) void k1_ball(const float* __restrict__ pos,
                                              int* __restrict__ idx)
{
  __shared__ float4 P[NN];  // 32 KB: x,y,z,S
  const int b = blockIdx.x >> 5;
  const int tile = blockIdx.x & 31;
  for (int i = threadIdx.x; i < NN; i += 64) {
    const float* p = pos + ((size_t)b*NN + i)*3;
    float x = p[0], y = p[1], z = p[2];
    // np: squares rounded individually, then sequential sum
    float s = __fadd_rn(__fadd_rn(__fmul_rn(x,x), __fmul_rn(y,y)), __fmul_rn(z,z));
    P[i] = make_float4(x, y, z, s);
  }
  __syncthreads();
  const int n = tile*64 + threadIdx.x;
  const float4 q = P[n];
  const float R2 = (float)(0.15 * 0.15);   // f32(0.0225000000000000011)
  int cnt = 0, first = n;
  bool has_first = false;
  int* ip = idx + ((size_t)b*NN + n)*KK;
  #pragma unroll 2
  for (int m = 0; m < NN; ++m) {
    float4 p = P[m];
    // einsum inner loop with FMA contraction, c ascending:
    float d = __fmul_rn(q.x, p.x);     // fma(x,x,0) == rnd(x*x)
    d = fmaf(q.y, p.y, d);
    d = fmaf(q.z, p.z, d);
    float sq = __fsub_rn(__fadd_rn(q.w, p.w), __fmul_rn(2.0f, d));
    if (!(sq > R2)) {
      if (!has_first) { first = m; has_first = true; }
      ip[cnt++] = m;
      if (cnt == KK) break;
    }
  }
  for (int k = cnt; k < KK; ++k) ip[k] = first;
}

// ---------------- K2: h1 per-channel sum/sumsq ----------------
// Channel-per-lane: lane c holds W1 column c (67 VGPRs). Row values broadcast
// via v_readlane. 4096 waves x 128 rows.
__global__ __launch_bounds__(256, 4) void k2_stats1(
    const float* __restrict__ pos, const float* __restrict__ feat,
    const float* __restrict__ W1, const int* __restrict__ idx,
    float* __restrict__ stats)   // [0:64) sum1, [64:128) sumsq1
{
  const int lane = threadIdx.x & 63;
  const int gw = (blockIdx.x * 256 + threadIdx.x) >> 6;
  float w1c[IN1];
  #pragma unroll
  for (int j = 0; j < IN1; ++j) w1c[j] = W1[j*CC1 + lane];
  const int RPW = TOTROWS / 4096;  // 128
  const int row0 = gw * RPW;
  float sum = 0.f, ssq = 0.f;
  for (int r = 0; r < RPW; ++r) {
    int row = row0 + r;
    int b = row >> 16;            // / (N*K)
    int n = (row >> 5) & (NN-1);  // / K % N
    int m = idx[row];             // wave-uniform
    const float* pm = pos + (b*NN + m)*3;
    const float* pn = pos + (b*NN + n)*3;
    float dx = pm[0] - pn[0];
    float dy = pm[1] - pn[1];
    float dz = pm[2] - pn[2];
    float f = feat[(b*NN + m)*DD + lane];
    float h0 = dx*w1c[0], h1 = dy*w1c[1], h2 = dz*w1c[2], h3 = 0.f;
    #pragma unroll
    for (int j = 0; j < 64; j += 4) {      // 4-way ILP on the fma chain
      h0 = fmaf(rl(f, j  ), w1c[3+j  ], h0);
      h1 = fmaf(rl(f, j+1), w1c[3+j+1], h1);
      h2 = fmaf(rl(f, j+2), w1c[3+j+2], h2);
      h3 = fmaf(rl(f, j+3), w1c[3+j+3], h3);
    }
    float h = (h0+h1) + (h2+h3);
    sum += h; ssq = fmaf(h, h, ssq);
  }
  atomicAdd(&stats[lane], sum);
  atomicAdd(&stats[64 + lane], ssq);
}

// ---------------- K3: main pass ----------------
// Recompute h1, bn1+relu -> a1 (lane=channel), h2 = a1 @ W2 (lane holds cols
// lane & lane+64), accumulate h2 stats, max over k, store pre-BN pooled f32.
__global__ __launch_bounds__(256, 2) void k3_main(
    const float* __restrict__ pos, const float* __restrict__ feat,
    const float* __restrict__ W1, const float* __restrict__ W2,
    const float* __restrict__ gamma1, const float* __restrict__ beta1,
    const int* __restrict__ idx, const float* __restrict__ stats1,
    float* __restrict__ stats2,  // [0:128) sum2, [128:256) sumsq2
    float* __restrict__ out_nf)
{
  const int lane = threadIdx.x & 63;
  const int gw = (blockIdx.x * 256 + threadIdx.x) >> 6;
  float w1c[IN1];
  #pragma unroll
  for (int j = 0; j < IN1; ++j) w1c[j] = W1[j*CC1 + lane];
  float w2a[CC1], w2b[CC1];
  #pragma unroll
  for (int j = 0; j < CC1; ++j) {
    w2a[j] = W2[j*CC2 + lane];
    w2b[j] = W2[j*CC2 + 64 + lane];
  }
  const float invc = 1.0f / (float)TOTROWS;
  float mean1 = stats1[lane] * invc;
  float var1  = stats1[64 + lane] * invc - mean1*mean1;
  float sc1 = rsqrtf(var1 + 1e-5f) * gamma1[lane];
  float sh1 = beta1[lane] - mean1 * sc1;
  float s2a = 0.f, q2a = 0.f, s2b = 0.f, q2b = 0.f;
  const int SPW = SITES / 4096;  // 4
  for (int si = 0; si < SPW; ++si) {
    int site = gw * SPW + si;
    int b = site >> 11, n = site & (NN-1);
    const float* pn = pos + (b*NN + n)*3;
    float cx = pn[0], cy = pn[1], cz = pn[2];
    float maxa = -3.0e38f, maxb = -3.0e38f;
    for (int k = 0; k < KK; ++k) {
      int m = idx[site*KK + k];
      const float* pm = pos + (b*NN + m)*3;
      float dx = pm[0] - cx, dy = pm[1] - cy, dz = pm[2] - cz;
      float f = feat[(b*NN + m)*DD + lane];
      float h0 = dx*w1c[0], h1 = dy*w1c[1], h2 = dz*w1c[2], h3 = 0.f;
      #pragma unroll
      for (int j = 0; j < 64; j += 4) {
        h0 = fmaf(rl(f, j  ), w1c[3+j  ], h0);
        h1 = fmaf(rl(f, j+1), w1c[3+j+1], h1);
        h2 = fmaf(rl(f, j+2), w1c[3+j+2], h2);
        h3 = fmaf(rl(f, j+3), w1c[3+j+3], h3);
      }
      float h = (h0+h1) + (h2+h3);
      float a = fmaxf(fmaf(h, sc1, sh1), 0.f);   // a1, lane = channel
      float ha0=0.f, ha1=0.f, hb0=0.f, hb1=0.f;
      #pragma unroll
      for (int j = 0; j < 64; j += 2) {
        float s0 = rl(a, j), s1 = rl(a, j+1);
        ha0 = fmaf(s0, w2a[j  ], ha0); hb0 = fmaf(s0, w2b[j  ], hb0);
        ha1 = fmaf(s1, w2a[j+1], ha1); hb1 = fmaf(s1, w2b[j+1], hb1);
      }
      float ha = ha0 + ha1, hb = hb0 + hb1;
      s2a += ha; q2a = fmaf(ha, ha, q2a);
      s2b += hb; q2b = fmaf(hb, hb, q2b);
      maxa = fmaxf(maxa, ha); maxb = fmaxf(maxb, hb);
    }
    out_nf[(size_t)site*CC2 + lane]      = maxa;  // pre-BN pooled
    out_nf[(size_t)site*CC2 + 64 + lane] = maxb;
  }
  atomicAdd(&stats2[lane],        s2a);
  atomicAdd(&stats2[64 + lane],   s2b);
  atomicAdd(&stats2[128 + lane],  q2a);
  atomicAdd(&stats2[192 + lane],  q2b);
}

// ---------------- K4: position pass-through ----------------
__global__ __launch_bounds__(256) void k4_pos(const float* __restrict__ pos,
                                              float* __restrict__ out) {
  int i = blockIdx.x*256 + threadIdx.x;
  out[i] = pos[i];
}

// ---------------- K5: bn2 + relu in place on pooled ----------------
__global__ __launch_bounds__(256) void k5_bn2(const float* __restrict__ g2,
                                              const float* __restrict__ be2,
                                              const float* __restrict__ stats2,
                                              float* __restrict__ out_nf) {
  int i = blockIdx.x*256 + threadIdx.x;
  int c = i & (CC2-1);
  const float invc = 1.0f / (float)TOTROWS;
  float mean = stats2[c] * invc;
  float var  = stats2[128 + c] * invc - mean*mean;
  float sc = rsqrtf(var + 1e-5f) * g2[c];
  float sh = be2[c] - mean * sc;
  float x = out_nf[i];
  out_nf[i] = fmaxf(fmaf(x, sc, sh), 0.f);
}

extern "C" void kernel_launch(void* const* d_in, const int* in_sizes, int n_in,
                              void* d_out, int out_size, void* d_ws, size_t ws_size,
                              hipStream_t stream) {
  const float* pos  = (const float*)d_in[0];
  const float* feat = (const float*)d_in[1];
  const float* W1   = (const float*)d_in[2];
  const float* g1   = (const float*)d_in[3];
  const float* be1  = (const float*)d_in[4];
  const float* W2   = (const float*)d_in[5];
  const float* g2   = (const float*)d_in[6];
  const float* be2  = (const float*)d_in[7];
  float* out = (float*)d_out;
  float* out_nf = out + (size_t)BB*NN*3;

  int*   idx   = (int*)d_ws;                                   // 2 MB
  float* stats = (float*)((char*)d_ws + (size_t)TOTROWS*4);    // 384 floats
  float* stats1 = stats;        // [0:64) sum1, [64:128) sumsq1
  float* stats2 = stats + 128;  // [0:128) sum2, [128:256) sumsq2

  hipMemsetAsync(stats, 0, 384*sizeof(float), stream);
  k1_ball  <<<256, 64, 0, stream>>>(pos, idx);
  k2_stats1<<<1024, 256, 0, stream>>>(pos, feat, W1, idx, stats1);
  k3_main  <<<1024, 256, 0, stream>>>(pos, feat, W1, W2, g1, be1, idx,
                                      stats1, stats2, out_nf);
  k4_pos   <<<(BB*NN*3)/256, 256, 0, stream>>>(pos, out);
  k5_bn2   <<<(BB*NN*CC2)/256, 256, 0, stream>>>(g2, be2, stats2, out_nf);
}

// Round 6
// 326.543 us; speedup vs baseline: 2.2044x; 2.2044x over previous
//
#include <hip/hip_runtime.h>
#include <hip/hip_bf16.h>

// LocalAggregation: B=8, N=2048, K=32, D=64, C1=64, C2=128, R=0.15, EPS=1e-5
// f32 storage, bf16-ified values. Pipeline:
//  k1  ball query (ballot compaction; f32 fma-chain selector — bit-matches ref)
//  kB  g[m,c1] = feat[m,:] @ W1[3:,c1]            (index-independent factor)
//  kC  stats1 over h1 = g[idx] + xyz@W1[:3]       (sum/sumsq per c1)
//  kC2 g'' = g*sc1+sh1 ; W1p = W1xyz*sc1          (fold BN1)
//  kD  per site: A1=relu(h1') bf16 -> MFMA @ W2 -> stats2 + pre-BN max-pool
//  k4  copy position ; k5 bn2+relu in place (monotone trick: gamma2>0)
// R5 bug fix: kB_g must be 1024 blocks (4096 waves x 4 rows = 16384 rows);
// 256 blocks left 3/4 of g poisoned -> absmax 5.47.

#define BB 8
#define NN 2048
#define KK 32
#define DD 64
#define CC1 64
#define CC2 128
#define TOTROWS (BB*NN*KK) // 524288
#define SITES (BB*NN)      // 16384

typedef __bf16 bf16x8 __attribute__((ext_vector_type(8)));
typedef float  f32x4  __attribute__((ext_vector_type(4)));

__device__ __forceinline__ float rl(float v, int l) {
  return __int_as_float(__builtin_amdgcn_readlane(__float_as_int(v), l));
}

// ---------------- K1: ball query, ballot compaction ----------------
// 512 blocks x 256 thr; block = (batch, 32-query group), wave = 8 queries.
// Selector arithmetic identical to the round-4 PASSING version.
__global__ __launch_bounds__(256) void k1_ball(const float* __restrict__ pos,
                                               int* __restrict__ idx)
{
  __shared__ float4 P[NN];  // 32 KB: x,y,z,S
  const int b = blockIdx.x >> 6;
  const int qbase = (blockIdx.x & 63) * 32;
  for (int i = threadIdx.x; i < NN; i += 256) {
    const float* p = pos + ((size_t)b*NN + i)*3;
    float x = p[0], y = p[1], z = p[2];
    float s = __fadd_rn(__fadd_rn(__fmul_rn(x,x), __fmul_rn(y,y)), __fmul_rn(z,z));
    P[i] = make_float4(x, y, z, s);
  }
  __syncthreads();
  const int wave = threadIdx.x >> 6, lane = threadIdx.x & 63;
  const float R2 = (float)(0.15 * 0.15);
  const unsigned long long lt = (lane == 63) ? 0x7fffffffffffffffull
                                             : ((1ull << lane) - 1ull);
  for (int qi = wave; qi < 32; qi += 4) {
    const int q = qbase + qi;
    const float4 Q = P[q];
    int* ip = idx + ((size_t)b*NN + q)*KK;
    int cnt = 0, first = -1;
    for (int step = 0; step < 32; ++step) {
      float4 p = P[step*64 + lane];
      float d = __fmul_rn(Q.x, p.x);
      d = fmaf(Q.y, p.y, d);
      d = fmaf(Q.z, p.z, d);
      float sq = __fsub_rn(__fadd_rn(Q.w, p.w), __fmul_rn(2.0f, d));
      bool in = !(sq > R2);
      unsigned long long mask = __ballot(in);
      if (first < 0 && mask) first = step*64 + (int)__builtin_ctzll(mask);
      int dst = cnt + (int)__popcll(mask & lt);
      if (in && dst < KK) ip[dst] = step*64 + lane;
      cnt += (int)__popcll(mask);
      if (cnt >= KK) break;
    }
    if (lane >= cnt && lane < KK) ip[lane] = first;  // cnt>=1 (self in ball)
  }
}

// ---------------- KB: g[m,c] = feat[m,:] @ W1[3:,c] ----------------
// channel-per-lane, readlane broadcast; 4096 waves x 4 rows = 16384 rows.
__global__ __launch_bounds__(256) void kB_g(const float* __restrict__ feat,
                                            const float* __restrict__ W1,
                                            float* __restrict__ g)
{
  const int lane = threadIdx.x & 63;
  const int gw = (blockIdx.x*256 + threadIdx.x) >> 6;
  float wf[DD];
  #pragma unroll
  for (int d = 0; d < DD; ++d) wf[d] = W1[(3+d)*CC1 + lane];
  for (int r = 0; r < 4; ++r) {
    int row = gw*4 + r;
    float f = feat[(size_t)row*DD + lane];
    float h0 = 0.f, h1 = 0.f, h2 = 0.f, h3 = 0.f;
    #pragma unroll
    for (int j = 0; j < 64; j += 4) {
      h0 = fmaf(rl(f, j  ), wf[j  ], h0);
      h1 = fmaf(rl(f, j+1), wf[j+1], h1);
      h2 = fmaf(rl(f, j+2), wf[j+2], h2);
      h3 = fmaf(rl(f, j+3), wf[j+3], h3);
    }
    g[(size_t)row*CC1 + lane] = (h0+h1) + (h2+h3);
  }
}

// ---------------- KC: stats1 over h1 = g[idx] + xyz part ----------------
// 4096 waves x 4 sites x 32 rows; lane = c1 channel.
__global__ __launch_bounds__(256) void kC_stats1(
    const float* __restrict__ pos, const float* __restrict__ g,
    const float* __restrict__ W1, const int* __restrict__ idx,
    float* __restrict__ stats1)
{
  const int lane = threadIdx.x & 63;
  const int gw = (blockIdx.x*256 + threadIdx.x) >> 6;
  const float w1x = W1[lane], w1y = W1[CC1 + lane], w1z = W1[2*CC1 + lane];
  float sum = 0.f, ssq = 0.f;
  for (int si = 0; si < 4; ++si) {
    int site = gw*4 + si;
    int b = site >> 11;
    const float* pc = pos + (size_t)site*3;
    float cx = pc[0], cy = pc[1], cz = pc[2];
    #pragma unroll 4
    for (int k = 0; k < KK; ++k) {
      int m = idx[site*KK + k];
      const float* pm = pos + ((size_t)b*NN + m)*3;
      float dx = pm[0]-cx, dy = pm[1]-cy, dz = pm[2]-cz;
      float h = g[((size_t)b*NN + m)*CC1 + lane];
      h = fmaf(dz, w1z, fmaf(dy, w1y, fmaf(dx, w1x, h)));
      sum += h; ssq = fmaf(h, h, ssq);
    }
  }
  atomicAdd(&stats1[lane], sum);
  atomicAdd(&stats1[64 + lane], ssq);
}

// ---------------- KC2: fold BN1 -> g'' and W1p ----------------
__global__ __launch_bounds__(256) void kC2_fold(
    const float* __restrict__ g, const float* __restrict__ W1,
    const float* __restrict__ gamma1, const float* __restrict__ beta1,
    const float* __restrict__ stats1,
    float* __restrict__ gpp, float* __restrict__ W1p)
{
  int i = blockIdx.x*256 + threadIdx.x;
  int c = i & (CC1-1);
  const float invc = 1.0f / (float)TOTROWS;
  float mean = stats1[c] * invc;
  float var  = stats1[64 + c] * invc - mean*mean;
  float sc = rsqrtf(var + 1e-5f) * gamma1[c];
  float sh = beta1[c] - mean * sc;
  gpp[i] = fmaf(g[i], sc, sh);
  if (i < 3*CC1) W1p[i] = W1[i] * sc;   // rows 0..2 of W1, channel c == i&63
}

// ---------------- KD: MFMA main pass ----------------
// wave = 8 sites; per site A1(32x64 bf16) @ W2(64x128 bf16) via 16x16x32 MFMA.
// A-frag: lane holds A[m=lane&15][k=quad*8+j]; B-frag: B[k=quad*8+j][n=lane&15];
// C/D: col=lane&15, row=quad*4+reg (guide §3, m89-verified).
__global__ __launch_bounds__(256, 2) void kD_mfma(
    const float* __restrict__ pos, const int* __restrict__ idx,
    const float* __restrict__ gpp, const float* __restrict__ W1p,
    const float* __restrict__ W2,
    float* __restrict__ stats2, float* __restrict__ out_nf)
{
  const int lane = threadIdx.x & 63;
  const int quad = lane >> 4;
  const int col  = lane & 15;
  const int gw = (blockIdx.x*256 + threadIdx.x) >> 6;

  bf16x8 Bf[2][8];
  #pragma unroll
  for (int kt = 0; kt < 2; ++kt)
    #pragma unroll
    for (int nt = 0; nt < 8; ++nt) {
      bf16x8 v;
      #pragma unroll
      for (int j = 0; j < 8; ++j)
        v[j] = (__bf16)W2[(kt*32 + quad*8 + j)*CC2 + nt*16 + col];
      Bf[kt][nt] = v;
    }
  float wx[2][8], wy[2][8], wz[2][8];
  #pragma unroll
  for (int kt = 0; kt < 2; ++kt)
    #pragma unroll
    for (int j = 0; j < 8; ++j) {
      int c = kt*32 + quad*8 + j;
      wx[kt][j] = W1p[c]; wy[kt][j] = W1p[64+c]; wz[kt][j] = W1p[128+c];
    }
  float ssum[8], ssq[8];
  #pragma unroll
  for (int nt = 0; nt < 8; ++nt) { ssum[nt] = 0.f; ssq[nt] = 0.f; }

  for (int si = 0; si < 8; ++si) {
    const int site = gw*8 + si;
    const int b = site >> 11;
    const float* pc = pos + (size_t)site*3;
    const float cx = pc[0], cy = pc[1], cz = pc[2];
    int mm[2]; float dx[2], dy[2], dz[2];
    #pragma unroll
    for (int mt = 0; mt < 2; ++mt) {
      mm[mt] = idx[site*KK + mt*16 + col];
      const float* pm = pos + ((size_t)b*NN + mm[mt])*3;
      dx[mt] = pm[0]-cx; dy[mt] = pm[1]-cy; dz[mt] = pm[2]-cz;
    }
    bf16x8 Af[2][2];
    #pragma unroll
    for (int mt = 0; mt < 2; ++mt)
      #pragma unroll
      for (int kt = 0; kt < 2; ++kt) {
        const float4* gp =
          (const float4*)(gpp + (((size_t)b*NN + mm[mt])*CC1 + kt*32 + quad*8));
        float4 g0 = gp[0], g1 = gp[1];
        float hv[8] = {g0.x,g0.y,g0.z,g0.w,g1.x,g1.y,g1.z,g1.w};
        bf16x8 v;
        #pragma unroll
        for (int j = 0; j < 8; ++j) {
          float h = fmaf(dz[mt], wz[kt][j],
                    fmaf(dy[mt], wy[kt][j],
                    fmaf(dx[mt], wx[kt][j], hv[j])));
          v[j] = (__bf16)fmaxf(h, 0.f);
        }
        Af[mt][kt] = v;
      }
    f32x4 acc[2][8];
    #pragma unroll
    for (int mt = 0; mt < 2; ++mt)
      #pragma unroll
      for (int nt = 0; nt < 8; ++nt) {
        f32x4 a = {0.f, 0.f, 0.f, 0.f};
        a = __builtin_amdgcn_mfma_f32_16x16x32_bf16(Af[mt][0], Bf[0][nt], a, 0, 0, 0);
        a = __builtin_amdgcn_mfma_f32_16x16x32_bf16(Af[mt][1], Bf[1][nt], a, 0, 0, 0);
        acc[mt][nt] = a;
      }
    #pragma unroll
    for (int nt = 0; nt < 8; ++nt) {
      float mx = -3.0e38f;
      #pragma unroll
      for (int mt = 0; mt < 2; ++mt)
        #pragma unroll
        for (int r = 0; r < 4; ++r) {
          float v = acc[mt][nt][r];
          ssum[nt] += v; ssq[nt] = fmaf(v, v, ssq[nt]);
          mx = fmaxf(mx, v);
        }
      mx = fmaxf(mx, __shfl_xor(mx, 16, 64));
      mx = fmaxf(mx, __shfl_xor(mx, 32, 64));
      if ((nt & 3) == quad)
        out_nf[(size_t)site*CC2 + nt*16 + col] = mx;   // pre-BN pooled
    }
  }
  #pragma unroll
  for (int nt = 0; nt < 8; ++nt) {
    float s = ssum[nt];
    s += __shfl_xor(s, 16, 64); s += __shfl_xor(s, 32, 64);
    float q = ssq[nt];
    q += __shfl_xor(q, 16, 64); q += __shfl_xor(q, 32, 64);
    if (lane < 16) {
      atomicAdd(&stats2[nt*16 + col], s);
      atomicAdd(&stats2[128 + nt*16 + col], q);
    }
  }
}

// ---------------- K4: position pass-through ----------------
__global__ __launch_bounds__(256) void k4_pos(const float* __restrict__ pos,
                                              float* __restrict__ out) {
  int i = blockIdx.x*256 + threadIdx.x;
  out[i] = pos[i];
}

// ---------------- K5: bn2 + relu in place on pooled ----------------
__global__ __launch_bounds__(256) void k5_bn2(const float* __restrict__ g2,
                                              const float* __restrict__ be2,
                                              const float* __restrict__ stats2,
                                              float* __restrict__ out_nf) {
  int i = blockIdx.x*256 + threadIdx.x;
  int c = i & (CC2-1);
  const float invc = 1.0f / (float)TOTROWS;
  float mean = stats2[c] * invc;
  float var  = stats2[128 + c] * invc - mean*mean;
  float sc = rsqrtf(var + 1e-5f) * g2[c];
  float sh = be2[c] - mean * sc;
  float x = out_nf[i];
  out_nf[i] = fmaxf(fmaf(x, sc, sh), 0.f);
}

extern "C" void kernel_launch(void* const* d_in, const int* in_sizes, int n_in,
                              void* d_out, int out_size, void* d_ws, size_t ws_size,
                              hipStream_t stream) {
  const float* pos  = (const float*)d_in[0];
  const float* feat = (const float*)d_in[1];
  const float* W1   = (const float*)d_in[2];
  const float* g1   = (const float*)d_in[3];
  const float* be1  = (const float*)d_in[4];
  const float* W2   = (const float*)d_in[5];
  const float* g2   = (const float*)d_in[6];
  const float* be2  = (const float*)d_in[7];
  float* out = (float*)d_out;
  float* out_nf = out + (size_t)BB*NN*3;

  char* w = (char*)d_ws;
  int*   idx    = (int*)w;                              // 2 MB
  float* stats  = (float*)(w + 2*1024*1024);            // 384 f32
  float* stats1 = stats;                                // [0:128)
  float* stats2 = stats + 128;                          // [0:256)
  float* W1p    = (float*)(w + 2*1024*1024 + 2048);     // 192 f32
  float* g      = (float*)(w + 2*1024*1024 + 4096);     // 4 MB
  float* gpp    = g + (size_t)SITES*CC1;                // 4 MB

  hipMemsetAsync(stats, 0, 384*sizeof(float), stream);
  k1_ball  <<<512, 256, 0, stream>>>(pos, idx);
  kB_g     <<<1024, 256, 0, stream>>>(feat, W1, g);     // 4096 waves x 4 rows
  kC_stats1<<<1024, 256, 0, stream>>>(pos, g, W1, idx, stats1);
  kC2_fold <<<SITES*CC1/256, 256, 0, stream>>>(g, W1, g1, be1, stats1, gpp, W1p);
  kD_mfma  <<<512, 256, 0, stream>>>(pos, idx, gpp, W1p, W2, stats2, out_nf);
  k4_pos   <<<(BB*NN*3)/256, 256, 0, stream>>>(pos, out);
  k5_bn2   <<<(SITES*CC2)/256, 256, 0, stream>>>(g2, be2, stats2, out_nf);
}